// Round 7
// baseline (419.984 us; speedup 1.0000x reference)
//
#include <hip/hip_runtime.h>
#include <hip/hip_bf16.h>

// Problem constants (S=2048, B=2, E=2048, H=32, D=64)
#define S_LEN 2048
#define BATCH 2
#define EMB   2048
#define NH    32
#define HD    64
#define M_ROWS (S_LEN * BATCH)   // 4096
#define QKV_N  (3 * EMB)         // 6144

typedef short bf16x8 __attribute__((ext_vector_type(8)));
typedef float f32x4  __attribute__((ext_vector_type(4)));

__device__ __forceinline__ unsigned short f2bf(float f) {
  unsigned int u = __float_as_uint(f);
  u += 0x7fffu + ((u >> 16) & 1u);       // round-to-nearest-even
  return (unsigned short)(u >> 16);
}
__device__ __forceinline__ float bf2f(unsigned short h) {
  return __uint_as_float(((unsigned int)h) << 16);
}
__device__ __forceinline__ void async_copy16(const void* g, void* lds) {
  __builtin_amdgcn_global_load_lds(
      (const __attribute__((address_space(1))) void*)g,
      (__attribute__((address_space(3))) void*)lds, 16, 0, 0);
}

#if __has_builtin(__builtin_amdgcn_exp2f)
#define EXP2F(x) __builtin_amdgcn_exp2f(x)
#else
#define EXP2F(x) __expf((x) * 0.6931471805599453f)
#endif

// ---------------- prep kernels ----------------

__global__ __launch_bounds__(256) void cast_to_bf16(
    const float* __restrict__ in, unsigned short* __restrict__ out, int n4) {
  int i = blockIdx.x * 256 + threadIdx.x;
  if (i >= n4) return;
  float4 v = reinterpret_cast<const float4*>(in)[i];
  ushort4 o;
  o.x = f2bf(v.x); o.y = f2bf(v.y); o.z = f2bf(v.z); o.w = f2bf(v.w);
  reinterpret_cast<ushort4*>(out)[i] = o;
}

// both weight transposes in one launch: z=0 qkv_w [E][3E], z=1 out_w [E][E]
__global__ __launch_bounds__(256) void transpose_cast2(
    const float* __restrict__ qkv_w, const float* __restrict__ out_w,
    unsigned short* __restrict__ qkvwT, unsigned short* __restrict__ outwT) {
  __shared__ float tile[32][33];
  const int z = blockIdx.z;
  const int C = z ? EMB : QKV_N;
  const int bc = blockIdx.x * 32;
  if (bc >= C) return;
  const float* in = z ? out_w : qkv_w;
  unsigned short* out = z ? outwT : qkvwT;
  const int br = blockIdx.y * 32;
  const int tx = threadIdx.x & 31, ty = threadIdx.x >> 5;   // ty 0..7
  #pragma unroll
  for (int rr = ty; rr < 32; rr += 8)
    tile[rr][tx] = in[(size_t)(br + rr) * C + bc + tx];
  __syncthreads();
  #pragma unroll
  for (int rr = ty; rr < 32; rr += 8)
    out[(size_t)(bc + rr) * EMB + br + tx] = f2bf(tile[tx][rr]);
}

// ---------------- QKV GEMM, BK=64, XOR-swizzled LDS, fused bias+RoPE+scatter ----
// (unchanged from R6 — measured at its structural plateau, MfmaUtil ~39%)

__global__ __launch_bounds__(256) void gemm_qkv(
    const unsigned short* __restrict__ A,
    const unsigned short* __restrict__ Wt,
    const float* __restrict__ bias,
    unsigned short* __restrict__ Qo,
    unsigned short* __restrict__ Ko,
    unsigned short* __restrict__ Vo) {
  __shared__ __align__(16) unsigned short As[128 * 64];
  __shared__ __align__(16) unsigned short Bs[128 * 64];
  const int tid = threadIdx.x;
  const int n0 = blockIdx.x * 128;
  const int m0 = blockIdx.y * 128;
  const int wave = tid >> 6, lane = tid & 63;
  const int wm = (wave >> 1) * 64, wn = (wave & 1) * 64;
  const int lm = lane & 15, lq = lane >> 4;
  const int K = 2048;

  const int srow = tid >> 3;                       // 0..31
  const int gch  = (tid & 7) ^ (srow & 7);
  const unsigned short* Ab = A  + (size_t)(m0 + srow) * K + gch * 8;
  const unsigned short* Bb = Wt + (size_t)(n0 + srow) * K + gch * 8;

  f32x4 acc[4][4] = {};

  for (int k0 = 0; k0 < K; k0 += 64) {
    #pragma unroll
    for (int rep = 0; rep < 4; rep++) {
      async_copy16(Ab + (size_t)rep * 32 * K + k0, As + (size_t)(tid + 256 * rep) * 8);
      async_copy16(Bb + (size_t)rep * 32 * K + k0, Bs + (size_t)(tid + 256 * rep) * 8);
    }
    __syncthreads();
    #pragma unroll
    for (int ks = 0; ks < 2; ks++) {
      bf16x8 a[4], b[4];
      #pragma unroll
      for (int i = 0; i < 4; i++) {
        const int R = wm + i*16 + lm;
        a[i] = *reinterpret_cast<const bf16x8*>(
            As + (size_t)R * 64 + (((ks*4 + lq) ^ (R & 7)) * 8));
      }
      #pragma unroll
      for (int j = 0; j < 4; j++) {
        const int R = wn + j*16 + lm;
        b[j] = *reinterpret_cast<const bf16x8*>(
            Bs + (size_t)R * 64 + (((ks*4 + lq) ^ (R & 7)) * 8));
      }
      #pragma unroll
      for (int i = 0; i < 4; i++)
        #pragma unroll
        for (int j = 0; j < 4; j++)
          acc[i][j] = __builtin_amdgcn_mfma_f32_16x16x32_bf16(a[i], b[j], acc[i][j], 0, 0, 0);
    }
    __syncthreads();
  }

  const int which = n0 >> 11;   // 0=q 1=k 2=v, uniform per block
  unsigned short* dst = (which == 0) ? Qo : (which == 1) ? Ko : Vo;
  float bv[4];
  #pragma unroll
  for (int j = 0; j < 4; j++) bv[j] = bias[n0 + wn + j*16 + lm];

  if (which < 2) {
    #pragma unroll
    for (int j = 0; j < 2; j++) {
      const int n = n0 + wn + j*16 + lm;
      const int e = n & (EMB - 1), h = e >> 6, d = e & 63;   // d < 32
      const float invf = EXP2F((float)d * -0.4152410118609203f);  // 10000^(-d/32)
      #pragma unroll
      for (int i = 0; i < 4; i++) {
        #pragma unroll
        for (int r = 0; r < 4; r++) {
          const int m = m0 + wm + i*16 + lq*4 + r;
          const int s = m >> 1, b = m & 1;
          const float v1 = acc[i][j][r]   + bv[j];
          const float v2 = acc[i][j+2][r] + bv[j+2];
          float sn, cs;
          __sincosf((float)s * invf, &sn, &cs);
          const size_t base = (((size_t)b * NH + h) * S_LEN + s) * HD + d;
          dst[base]      = f2bf(v1 * cs - v2 * sn);
          dst[base + 32] = f2bf(v2 * cs + v1 * sn);
        }
      }
    }
  } else {
    #pragma unroll
    for (int j = 0; j < 4; j++) {
      const int n = n0 + wn + j*16 + lm;
      const int e = n & (EMB - 1), h = e >> 6, d = e & 63;
      #pragma unroll
      for (int i = 0; i < 4; i++) {
        #pragma unroll
        for (int r = 0; r < 4; r++) {
          const int m = m0 + wm + i*16 + lq*4 + r;
          const int s = m >> 1, b = m & 1;
          dst[(((size_t)b * NH + h) * S_LEN + s) * HD + d] = f2bf(acc[i][j][r] + bv[j]);
        }
      }
    }
  }
}

// ---------------- V [B,H,S,D] -> VT [B,H,D,S] ----------------

__global__ __launch_bounds__(256) void transpose_v(
    const unsigned short* __restrict__ V, unsigned short* __restrict__ VT) {
  __shared__ unsigned short t[64][65];
  const int bh = blockIdx.y;
  const int s0 = blockIdx.x * 64;
  const int tx = threadIdx.x & 63, ty = threadIdx.x >> 6;  // ty 0..3
  const unsigned short* src = V + ((size_t)bh * S_LEN + s0) * HD;
  #pragma unroll
  for (int r = ty; r < 64; r += 4)
    t[r][tx] = src[(size_t)r * HD + tx];
  __syncthreads();
  unsigned short* dst = VT + (size_t)bh * HD * S_LEN + s0;
  #pragma unroll
  for (int r = ty; r < 64; r += 4)
    dst[(size_t)r * S_LEN + tx] = t[tx][r];
}

// ---------------- Flash attention (causal), bf16 MFMA, fixed-max softmax ----------------
// Block = (head, strip pair s / 31-s), strips of 64 q-rows, 4 waves x 16 rows
// per strip -> grid 64x16 = 1024 blocks (2x occupancy vs 128-row pairing).
// One tile loop serves both strips; K/V double-buffered via global_load_lds,
// ONE barrier per tile (prefetch t+1 issued before compute t). Fixed-max
// softmax: per-lane l partials, no K-loop cross-lane ops.

__global__ __launch_bounds__(256) void attn_kernel(
    const unsigned short* __restrict__ Q,
    const unsigned short* __restrict__ K,
    const unsigned short* __restrict__ VT,
    unsigned short* __restrict__ ctx) {
  const int bh = blockIdx.x;               // b*32+h
  const int p  = blockIdx.y;               // 0..15 strip pair
  const int tid = threadIdx.x;
  const int wave = tid >> 6, lane = tid & 63;
  const int lm = lane & 15, lq = lane >> 4;
  const int b = bh >> 5, h = bh & 31;
  const char* Qb8 = (const char*)(Q  + (size_t)bh * S_LEN * HD);
  const char* Kb8 = (const char*)(K  + (size_t)bh * S_LEN * HD);
  const char* Vb8 = (const char*)(VT + (size_t)bh * HD * S_LEN);

  __shared__ __align__(16) unsigned short Ks[2][2][64][32];  // [buf][half][row][32]
  __shared__ __align__(16) unsigned short Vs[2][2][64][32];
  __shared__ __align__(16) unsigned short Pbuf[4][16][72];
  unsigned short* Pw = &Pbuf[wave][0][0];

  const float C = 0.18033688011112042f;    // (1/8) * log2(e)
  const int rA = p * 64 + wave * 16;       // light strip rows rA..rA+15
  const int rB = (31 - p) * 64 + wave * 16;
  const int nt = 32 - p;                   // heavy strip's 64-key tile count

  const int srw = tid >> 2, sc16 = (tid & 3) * 16;

  // Q fragments (A-layout): rows r+lm, k = ks*32 + lq*8
  bf16x8 qf[2][2];                         // [strip][ks]
  #pragma unroll
  for (int s = 0; s < 2; s++) {
    const int rr = (s == 0) ? rA : rB;
    #pragma unroll
    for (int ks = 0; ks < 2; ks++)
      qf[s][ks] = *reinterpret_cast<const bf16x8*>(
          Qb8 + (size_t)(rr + lm) * 128 + ks*64 + lq*16);
  }

  f32x4 O[2][4] = {};
  float l[2][4] = {};

  // stage tile 0 into buf 0
  {
    char* kd = (char*)&Ks[0][0][0][0];
    char* vd = (char*)&Vs[0][0][0][0];
    async_copy16(Kb8 + (size_t)srw * 128      + sc16, kd        + tid*16);
    async_copy16(Kb8 + (size_t)srw * 128 + 64 + sc16, kd + 4096 + tid*16);
    async_copy16(Vb8 + (size_t)srw * 4096      + sc16, vd        + tid*16);
    async_copy16(Vb8 + (size_t)srw * 4096 + 64 + sc16, vd + 4096 + tid*16);
  }
  __syncthreads();

  for (int t = 0; t < nt; t++) {
    const int t0 = t * 64;
    const int buf = t & 1;

    if (t + 1 < nt) {
      const int t1 = t0 + 64;
      char* kd = (char*)&Ks[buf ^ 1][0][0][0];
      char* vd = (char*)&Vs[buf ^ 1][0][0][0];
      async_copy16(Kb8 + (size_t)(t1 + srw) * 128      + sc16, kd        + tid*16);
      async_copy16(Kb8 + (size_t)(t1 + srw) * 128 + 64 + sc16, kd + 4096 + tid*16);
      async_copy16(Vb8 + (size_t)srw * 4096 + t1*2      + sc16, vd        + tid*16);
      async_copy16(Vb8 + (size_t)srw * 4096 + t1*2 + 64 + sc16, vd + 4096 + tid*16);
    }

    const char* KsB = (const char*)&Ks[buf][0][0][0];
    const char* VsB = (const char*)&Vs[buf][0][0][0];

    #pragma unroll
    for (int s = 0; s < 2; s++) {
      const int rr = (s == 0) ? rA : rB;
      if (t0 <= rr + 15) {
        const bool clean = (t0 + 63 <= rr);
        const int jmax = clean ? 4 : min(4, ((rr + 15 - t0) >> 4) + 1);
        const int kslim = (jmax + 1) >> 1;

        // S = Q K^T from LDS halves
        f32x4 sc[4] = {};
        #pragma unroll
        for (int ks = 0; ks < 2; ks++) {
          bf16x8 kf[4];
          #pragma unroll
          for (int j = 0; j < 4; j++)
            if (j < jmax)
              kf[j] = *reinterpret_cast<const bf16x8*>(
                  KsB + ks*4096 + (j*16 + lm)*64 + lq*16);
          #pragma unroll
          for (int j = 0; j < 4; j++)
            if (j < jmax)
              sc[j] = __builtin_amdgcn_mfma_f32_16x16x32_bf16(
                  qf[s][ks], kf[j], sc[j], 0, 0, 0);
        }

        // exp (fixed max), per-lane l, write P
        if (clean) {
          #pragma unroll
          for (int j = 0; j < 4; j++)
            #pragma unroll
            for (int r = 0; r < 4; r++) {
              const float pe = EXP2F(sc[j][r] * C);
              l[s][r] += pe;
              Pw[(lq*4 + r) * 72 + j*16 + lm] = f2bf(pe);
            }
        } else {
          #pragma unroll
          for (int j = 0; j < 4; j++)
            if (j < jmax)
              #pragma unroll
              for (int r = 0; r < 4; r++) {
                const int srow = rr + lq*4 + r;
                const int tcol = t0 + j*16 + lm;
                const float pe = (tcol <= srow) ? EXP2F(sc[j][r] * C) : 0.0f;
                l[s][r] += pe;
                Pw[(lq*4 + r) * 72 + j*16 + lm] = f2bf(pe);
              }
          if (jmax & 1) {                  // zero-fill block jmax for PV half
            #pragma unroll
            for (int r = 0; r < 4; r++)
              Pw[(lq*4 + r) * 72 + jmax*16 + lm] = 0;
          }
        }

        // O += P V
        #pragma unroll
        for (int ks = 0; ks < 2; ks++) {
          if (ks < kslim) {
            bf16x8 pf = *reinterpret_cast<const bf16x8*>(Pw + lm*72 + ks*32 + lq*8);
            bf16x8 vf[4];
            #pragma unroll
            for (int j = 0; j < 4; j++)
              vf[j] = *reinterpret_cast<const bf16x8*>(
                  VsB + ks*4096 + (j*16 + lm)*64 + lq*16);
            #pragma unroll
            for (int j = 0; j < 4; j++)
              O[s][j] = __builtin_amdgcn_mfma_f32_16x16x32_bf16(
                  pf, vf[j], O[s][j], 0, 0, 0);
          }
        }
      }
    }
    __syncthreads();   // compute(t) done; stage(t+1) drained
  }

  // epilogue: reduce l across 16-lane column groups, scale, store ctx [S,B,E]
  #pragma unroll
  for (int s = 0; s < 2; s++) {
    const int rr = (s == 0) ? rA : rB;
    #pragma unroll
    for (int r = 0; r < 4; r++) {
      float sum = l[s][r];
      sum += __shfl_xor(sum, 1, 64);
      sum += __shfl_xor(sum, 2, 64);
      sum += __shfl_xor(sum, 4, 64);
      sum += __shfl_xor(sum, 8, 64);
      const float inv = 1.0f / sum;
      const int srow = rr + lq*4 + r;
      #pragma unroll
      for (int j = 0; j < 4; j++) {
        const int d = j*16 + lm;
        ctx[((size_t)srow * BATCH + b) * EMB + h*HD + d] = f2bf(O[s][j][r] * inv);
      }
    }
  }
}

// ---------------- Output GEMM: ctx x outWt + bias -> f32, double-buffered ----------------
// Grid 512 blocks = 2/CU regardless of LDS, so 64 KB dbuf is free; single
// barrier per K-iter with 32 MFMA of issue-to-drain distance.

__global__ __launch_bounds__(256) void gemm_out(
    const unsigned short* __restrict__ A,
    const unsigned short* __restrict__ Wt,
    const float* __restrict__ bias,
    float* __restrict__ out) {
  __shared__ __align__(16) unsigned short As[2][128 * 64];
  __shared__ __align__(16) unsigned short Bs[2][128 * 64];
  const int tid = threadIdx.x;
  const int n0 = blockIdx.x * 128;
  const int m0 = blockIdx.y * 128;
  const int wave = tid >> 6, lane = tid & 63;
  const int wm = (wave >> 1) * 64, wn = (wave & 1) * 64;
  const int lm = lane & 15, lq = lane >> 4;
  const int K = 2048;

  const int srow = tid >> 3;
  const int gch  = (tid & 7) ^ (srow & 7);
  const unsigned short* Ab = A  + (size_t)(m0 + srow) * K + gch * 8;
  const unsigned short* Bb = Wt + (size_t)(n0 + srow) * K + gch * 8;

  f32x4 acc[4][4] = {};

  // stage tile 0
  #pragma unroll
  for (int rep = 0; rep < 4; rep++) {
    async_copy16(Ab + (size_t)rep * 32 * K, As[0] + (size_t)(tid + 256 * rep) * 8);
    async_copy16(Bb + (size_t)rep * 32 * K, Bs[0] + (size_t)(tid + 256 * rep) * 8);
  }
  __syncthreads();

  for (int kt = 0; kt < 32; kt++) {
    const int buf = kt & 1;
    if (kt + 1 < 32) {
      const int k1 = (kt + 1) * 64;
      #pragma unroll
      for (int rep = 0; rep < 4; rep++) {
        async_copy16(Ab + (size_t)rep * 32 * K + k1, As[buf ^ 1] + (size_t)(tid + 256 * rep) * 8);
        async_copy16(Bb + (size_t)rep * 32 * K + k1, Bs[buf ^ 1] + (size_t)(tid + 256 * rep) * 8);
      }
    }
    #pragma unroll
    for (int ks = 0; ks < 2; ks++) {
      bf16x8 a[4], b[4];
      #pragma unroll
      for (int i = 0; i < 4; i++) {
        const int R = wm + i*16 + lm;
        a[i] = *reinterpret_cast<const bf16x8*>(
            As[buf] + (size_t)R * 64 + (((ks*4 + lq) ^ (R & 7)) * 8));
      }
      #pragma unroll
      for (int j = 0; j < 4; j++) {
        const int R = wn + j*16 + lm;
        b[j] = *reinterpret_cast<const bf16x8*>(
            Bs[buf] + (size_t)R * 64 + (((ks*4 + lq) ^ (R & 7)) * 8));
      }
      #pragma unroll
      for (int i = 0; i < 4; i++)
        #pragma unroll
        for (int j = 0; j < 4; j++)
          acc[i][j] = __builtin_amdgcn_mfma_f32_16x16x32_bf16(a[i], b[j], acc[i][j], 0, 0, 0);
    }
    __syncthreads();
  }

  #pragma unroll
  for (int j = 0; j < 4; j++) {
    const int n = n0 + wn + j*16 + lm;
    const float bv = bias[n];
    #pragma unroll
    for (int i = 0; i < 4; i++) {
      #pragma unroll
      for (int r = 0; r < 4; r++) {
        const int m = m0 + wm + i*16 + lq*4 + r;
        out[(size_t)m * EMB + n] = acc[i][j][r] + bv;
      }
    }
  }
}

// ---------------- host launcher ----------------

extern "C" void kernel_launch(void* const* d_in, const int* in_sizes, int n_in,
                              void* d_out, int out_size, void* d_ws, size_t ws_size,
                              hipStream_t stream) {
  const float* hidden = (const float*)d_in[0];
  const float* qkv_w  = (const float*)d_in[1];
  const float* qkv_b  = (const float*)d_in[2];
  const float* out_w  = (const float*)d_in[3];
  const float* out_b  = (const float*)d_in[4];
  float* out = (float*)d_out;

  unsigned short* ws = (unsigned short*)d_ws;
  unsigned short* hbf   = ws;                                  // 4096*2048
  unsigned short* qkvwT = hbf   + (size_t)M_ROWS * EMB;        // 6144*2048
  unsigned short* outwT = qkvwT + (size_t)QKV_N * EMB;         // 2048*2048
  unsigned short* Qb    = outwT + (size_t)EMB * EMB;           // 64*2048*64 each
  unsigned short* Kb    = Qb    + (size_t)64 * S_LEN * HD;
  unsigned short* Vb    = Kb    + (size_t)64 * S_LEN * HD;
  unsigned short* VTb   = Vb    + (size_t)64 * S_LEN * HD;
  unsigned short* ctx   = VTb   + (size_t)64 * S_LEN * HD;     // 4096*2048

  // 1. casts / transposes
  cast_to_bf16<<<(M_ROWS * EMB / 4) / 256, 256, 0, stream>>>(hidden, hbf, M_ROWS * EMB / 4);
  transpose_cast2<<<dim3(QKV_N / 32, EMB / 32, 2), 256, 0, stream>>>(qkv_w, out_w, qkvwT, outwT);

  // 2. fused QKV projection + bias + RoPE + scatter
  gemm_qkv<<<dim3(QKV_N / 128, M_ROWS / 128), 256, 0, stream>>>(hbf, qkvwT, qkv_b, Qb, Kb, Vb);

  // 3. V transpose
  transpose_v<<<dim3(S_LEN / 64, 64), 256, 0, stream>>>(Vb, VTb);

  // 4. causal flash attention (64-row strip pairs, dbuf K/V, 1 barrier/tile)
  attn_kernel<<<dim3(64, 16), 256, 0, stream>>>(Qb, Kb, VTb, ctx);

  // 5. output projection (double-buffered)
  gemm_out<<<dim3(EMB / 128, M_ROWS / 128), 256, 0, stream>>>(ctx, outwT, out_b, out);
}

// Round 8
// 414.166 us; speedup vs baseline: 1.0140x; 1.0140x over previous
//
#include <hip/hip_runtime.h>
#include <hip/hip_bf16.h>

// Problem constants (S=2048, B=2, E=2048, H=32, D=64)
#define S_LEN 2048
#define BATCH 2
#define EMB   2048
#define NH    32
#define HD    64
#define M_ROWS (S_LEN * BATCH)   // 4096
#define QKV_N  (3 * EMB)         // 6144

typedef short bf16x8 __attribute__((ext_vector_type(8)));
typedef float f32x4  __attribute__((ext_vector_type(4)));

__device__ __forceinline__ unsigned short f2bf(float f) {
  unsigned int u = __float_as_uint(f);
  u += 0x7fffu + ((u >> 16) & 1u);       // round-to-nearest-even
  return (unsigned short)(u >> 16);
}
__device__ __forceinline__ unsigned int pkbf(float a, float b) {
  __hip_bfloat162 t = __float22bfloat162_rn(float2{a, b});   // v_cvt_pk_bf16_f32
  return *reinterpret_cast<unsigned int*>(&t);
}
__device__ __forceinline__ void async_copy16(const void* g, void* lds) {
  __builtin_amdgcn_global_load_lds(
      (const __attribute__((address_space(1))) void*)g,
      (__attribute__((address_space(3))) void*)lds, 16, 0, 0);
}

#if __has_builtin(__builtin_amdgcn_exp2f)
#define EXP2F(x) __builtin_amdgcn_exp2f(x)
#else
#define EXP2F(x) __expf((x) * 0.6931471805599453f)
#endif

// ---------------- prep kernels ----------------

__global__ __launch_bounds__(256) void cast_to_bf16(
    const float* __restrict__ in, unsigned short* __restrict__ out, int n4) {
  int i = blockIdx.x * 256 + threadIdx.x;
  if (i >= n4) return;
  float4 v = reinterpret_cast<const float4*>(in)[i];
  ushort4 o;
  o.x = f2bf(v.x); o.y = f2bf(v.y); o.z = f2bf(v.z); o.w = f2bf(v.w);
  reinterpret_cast<ushort4*>(out)[i] = o;
}

// both weight transposes in one launch: z=0 qkv_w [E][3E], z=1 out_w [E][E]
__global__ __launch_bounds__(256) void transpose_cast2(
    const float* __restrict__ qkv_w, const float* __restrict__ out_w,
    unsigned short* __restrict__ qkvwT, unsigned short* __restrict__ outwT) {
  __shared__ float tile[32][33];
  const int z = blockIdx.z;
  const int C = z ? EMB : QKV_N;
  const int bc = blockIdx.x * 32;
  if (bc >= C) return;
  const float* in = z ? out_w : qkv_w;
  unsigned short* out = z ? outwT : qkvwT;
  const int br = blockIdx.y * 32;
  const int tx = threadIdx.x & 31, ty = threadIdx.x >> 5;   // ty 0..7
  #pragma unroll
  for (int rr = ty; rr < 32; rr += 8)
    tile[rr][tx] = in[(size_t)(br + rr) * C + bc + tx];
  __syncthreads();
  #pragma unroll
  for (int rr = ty; rr < 32; rr += 8)
    out[(size_t)(bc + rr) * EMB + br + tx] = f2bf(tile[tx][rr]);
}

// ---------------- QKV GEMM, BK=64, XOR-swizzled LDS, fused bias+RoPE+scatter ----
// Q additionally pre-scaled by (1/8)*log2(e) so attention's exp2 needs no mul.

__global__ __launch_bounds__(256) void gemm_qkv(
    const unsigned short* __restrict__ A,
    const unsigned short* __restrict__ Wt,
    const float* __restrict__ bias,
    unsigned short* __restrict__ Qo,
    unsigned short* __restrict__ Ko,
    unsigned short* __restrict__ Vo) {
  __shared__ __align__(16) unsigned short As[128 * 64];
  __shared__ __align__(16) unsigned short Bs[128 * 64];
  const int tid = threadIdx.x;
  const int n0 = blockIdx.x * 128;
  const int m0 = blockIdx.y * 128;
  const int wave = tid >> 6, lane = tid & 63;
  const int wm = (wave >> 1) * 64, wn = (wave & 1) * 64;
  const int lm = lane & 15, lq = lane >> 4;
  const int K = 2048;

  const int srow = tid >> 3;                       // 0..31
  const int gch  = (tid & 7) ^ (srow & 7);
  const unsigned short* Ab = A  + (size_t)(m0 + srow) * K + gch * 8;
  const unsigned short* Bb = Wt + (size_t)(n0 + srow) * K + gch * 8;

  f32x4 acc[4][4] = {};

  for (int k0 = 0; k0 < K; k0 += 64) {
    #pragma unroll
    for (int rep = 0; rep < 4; rep++) {
      async_copy16(Ab + (size_t)rep * 32 * K + k0, As + (size_t)(tid + 256 * rep) * 8);
      async_copy16(Bb + (size_t)rep * 32 * K + k0, Bs + (size_t)(tid + 256 * rep) * 8);
    }
    __syncthreads();
    #pragma unroll
    for (int ks = 0; ks < 2; ks++) {
      bf16x8 a[4], b[4];
      #pragma unroll
      for (int i = 0; i < 4; i++) {
        const int R = wm + i*16 + lm;
        a[i] = *reinterpret_cast<const bf16x8*>(
            As + (size_t)R * 64 + (((ks*4 + lq) ^ (R & 7)) * 8));
      }
      #pragma unroll
      for (int j = 0; j < 4; j++) {
        const int R = wn + j*16 + lm;
        b[j] = *reinterpret_cast<const bf16x8*>(
            Bs + (size_t)R * 64 + (((ks*4 + lq) ^ (R & 7)) * 8));
      }
      #pragma unroll
      for (int i = 0; i < 4; i++)
        #pragma unroll
        for (int j = 0; j < 4; j++)
          acc[i][j] = __builtin_amdgcn_mfma_f32_16x16x32_bf16(a[i], b[j], acc[i][j], 0, 0, 0);
    }
    __syncthreads();
  }

  const int which = n0 >> 11;   // 0=q 1=k 2=v, uniform per block
  unsigned short* dst = (which == 0) ? Qo : (which == 1) ? Ko : Vo;
  float bv[4];
  #pragma unroll
  for (int j = 0; j < 4; j++) bv[j] = bias[n0 + wn + j*16 + lm];

  if (which < 2) {
    const float osc = (which == 0) ? 0.18033688011112042f : 1.0f;  // (1/8)*log2(e)
    #pragma unroll
    for (int j = 0; j < 2; j++) {
      const int n = n0 + wn + j*16 + lm;
      const int e = n & (EMB - 1), h = e >> 6, d = e & 63;   // d < 32
      const float invf = EXP2F((float)d * -0.4152410118609203f);  // 10000^(-d/32)
      #pragma unroll
      for (int i = 0; i < 4; i++) {
        #pragma unroll
        for (int r = 0; r < 4; r++) {
          const int m = m0 + wm + i*16 + lq*4 + r;
          const int s = m >> 1, b = m & 1;
          const float v1 = acc[i][j][r]   + bv[j];
          const float v2 = acc[i][j+2][r] + bv[j+2];
          float sn, cs;
          __sincosf((float)s * invf, &sn, &cs);
          const size_t base = (((size_t)b * NH + h) * S_LEN + s) * HD + d;
          dst[base]      = f2bf((v1 * cs - v2 * sn) * osc);
          dst[base + 32] = f2bf((v2 * cs + v1 * sn) * osc);
        }
      }
    }
  } else {
    #pragma unroll
    for (int j = 0; j < 4; j++) {
      const int n = n0 + wn + j*16 + lm;
      const int e = n & (EMB - 1), h = e >> 6, d = e & 63;
      #pragma unroll
      for (int i = 0; i < 4; i++) {
        #pragma unroll
        for (int r = 0; r < 4; r++) {
          const int m = m0 + wm + i*16 + lq*4 + r;
          const int s = m >> 1, b = m & 1;
          dst[(((size_t)b * NH + h) * S_LEN + s) * HD + d] = f2bf(acc[i][j][r] + bv[j]);
        }
      }
    }
  }
}

// ---------------- V [B,H,S,D] -> VT [B,H,D,S] ----------------

__global__ __launch_bounds__(256) void transpose_v(
    const unsigned short* __restrict__ V, unsigned short* __restrict__ VT) {
  __shared__ unsigned short t[64][65];
  const int bh = blockIdx.y;
  const int s0 = blockIdx.x * 64;
  const int tx = threadIdx.x & 63, ty = threadIdx.x >> 6;  // ty 0..3
  const unsigned short* src = V + ((size_t)bh * S_LEN + s0) * HD;
  #pragma unroll
  for (int r = ty; r < 64; r += 4)
    t[r][tx] = src[(size_t)r * HD + tx];
  __syncthreads();
  unsigned short* dst = VT + (size_t)bh * HD * S_LEN + s0;
  #pragma unroll
  for (int r = ty; r < 64; r += 4)
    dst[(size_t)r * S_LEN + tx] = t[tx][r];
}

// ---------------- Flash attention (causal), register-direct P path ----------------
// Block = (head, strip pair p/15-p), 4 waves x 32 q-rows per strip (R6 partition).
// S^T = mfma(K_frag, Q_frag): C-layout col = q-row m, row = key t. After exp2
// (Q pre-scaled), P^T packs IN REGISTERS (v_cvt_pk_bf16_f32) into the PV
// B-operand; PV computes O^T = V^T * P^T with a permuted-k 16x16x32 MFMA
// (A-frag reads V^T at the matching permuted t-slices). No P LDS round-trip.
// K/V double-buffered, one barrier per tile.

__global__ __launch_bounds__(256) void attn_kernel(
    const unsigned short* __restrict__ Q,
    const unsigned short* __restrict__ K,
    const unsigned short* __restrict__ VT,
    unsigned short* __restrict__ ctx) {
  const int bh = blockIdx.x;               // b*32+h
  const int p  = blockIdx.y;               // 0..7 strip pair
  const int tid = threadIdx.x;
  const int wave = tid >> 6, lane = tid & 63;
  const int lm = lane & 15, lq = lane >> 4;
  const int b = bh >> 5, h = bh & 31;
  const char* Qb8 = (const char*)(Q  + (size_t)bh * S_LEN * HD);
  const char* Kb8 = (const char*)(K  + (size_t)bh * S_LEN * HD);
  const char* Vb8 = (const char*)(VT + (size_t)bh * HD * S_LEN);

  __shared__ __align__(16) unsigned short Ks[2][2][64][32];  // [buf][half][row][32]
  __shared__ __align__(16) unsigned short Vs[2][2][64][32];

  const int rA = p * 128 + wave * 32;
  const int rB = (15 - p) * 128 + wave * 32;
  const int nt = ((15 - p) * 128 >> 6) + 2;  // heavy strip tile count

  const int srw = tid >> 2, sc16 = (tid & 3) * 16;

  // Q fragments (rows rr+i*16+lm, k-contiguous) — used as MFMA B operand
  bf16x8 qf[2][2][2];                      // [strip][i][ks]
  #pragma unroll
  for (int s = 0; s < 2; s++) {
    const int rr = s ? rB : rA;
    #pragma unroll
    for (int i = 0; i < 2; i++)
      #pragma unroll
      for (int ks = 0; ks < 2; ks++)
        qf[s][i][ks] = *reinterpret_cast<const bf16x8*>(
            Qb8 + (size_t)(rr + i*16 + lm) * 128 + ks*64 + lq*16);
  }

  f32x4 O[2][2][4] = {};                   // [strip][i][d-tile] — O^T C-layout
  float l[2][2] = {};                      // per-lane scalar (m = lm fixed)

  // stage tile 0 into buf 0
  {
    char* kd = (char*)&Ks[0][0][0][0];
    char* vd = (char*)&Vs[0][0][0][0];
    async_copy16(Kb8 + (size_t)srw * 128      + sc16, kd        + tid*16);
    async_copy16(Kb8 + (size_t)srw * 128 + 64 + sc16, kd + 4096 + tid*16);
    async_copy16(Vb8 + (size_t)srw * 4096      + sc16, vd        + tid*16);
    async_copy16(Vb8 + (size_t)srw * 4096 + 64 + sc16, vd + 4096 + tid*16);
  }
  __syncthreads();

  for (int t = 0; t < nt; t++) {
    const int t0 = t * 64;
    const int buf = t & 1;

    if (t + 1 < nt) {
      const int t1 = t0 + 64;
      char* kd = (char*)&Ks[buf ^ 1][0][0][0];
      char* vd = (char*)&Vs[buf ^ 1][0][0][0];
      async_copy16(Kb8 + (size_t)(t1 + srw) * 128      + sc16, kd        + tid*16);
      async_copy16(Kb8 + (size_t)(t1 + srw) * 128 + 64 + sc16, kd + 4096 + tid*16);
      async_copy16(Vb8 + (size_t)srw * 4096 + t1*2      + sc16, vd        + tid*16);
      async_copy16(Vb8 + (size_t)srw * 4096 + t1*2 + 64 + sc16, vd + 4096 + tid*16);
    }

    const char* KsB = (const char*)&Ks[buf][0][0][0];
    const char* VsB = (const char*)&Vs[buf][0][0][0];

    #pragma unroll
    for (int s = 0; s < 2; s++) {
      const int rr = s ? rB : rA;
      if (t0 <= rr + 31) {
        const bool clean = (t0 + 63 <= rr);
        int jm[2];
        jm[1] = clean ? 4 : (((rr + 31 - t0) >> 4) + 1);
        jm[0] = clean ? 4 : ((t0 > rr + 15) ? 0 : (((rr + 15 - t0) >> 4) + 1));

        // S^T = K · Q^T  (kf in A position, qf in B position)
        f32x4 sc[2][4] = {};
        #pragma unroll
        for (int ks = 0; ks < 2; ks++) {
          bf16x8 kf[4];
          #pragma unroll
          for (int j = 0; j < 4; j++)
            if (j < jm[1])
              kf[j] = *reinterpret_cast<const bf16x8*>(
                  KsB + ks*4096 + (j*16 + lm)*64 + lq*16);
          #pragma unroll
          for (int i = 0; i < 2; i++)
            #pragma unroll
            for (int j = 0; j < 4; j++)
              if (j < jm[i])
                sc[i][j] = __builtin_amdgcn_mfma_f32_16x16x32_bf16(
                    kf[j], qf[s][i][ks], sc[i][j], 0, 0, 0);
        }

        // exp2 + pack P^T directly into PV B-fragments (no LDS)
        unsigned int pb[2][2][4];          // [i][t-window][reg]
        #pragma unroll
        for (int i = 0; i < 2; i++) {
          #pragma unroll
          for (int j = 0; j < 4; j++) {
            const int w = j >> 1, rbase = (j & 1) * 2;
            if (j < jm[i]) {
              const bool full = clean || (t0 + j*16 + 15 <= rr + i*16);
              float pe[4];
              #pragma unroll
              for (int r = 0; r < 4; r++) {
                float v = EXP2F(sc[i][j][r]);
                if (!full) {
                  const int tt = t0 + j*16 + lq*4 + r;
                  const int mm = rr + i*16 + lm;
                  v = (tt <= mm) ? v : 0.0f;
                }
                pe[r] = v;
              }
              l[s][i] += (pe[0] + pe[1]) + (pe[2] + pe[3]);
              pb[i][w][rbase]     = pkbf(pe[0], pe[1]);
              pb[i][w][rbase + 1] = pkbf(pe[2], pe[3]);
            } else {
              pb[i][w][rbase] = 0; pb[i][w][rbase + 1] = 0;
            }
          }
        }

        // O^T += V^T · P^T  (permuted-k: A-frag reads t = w*32 + {4lq..+3, 16+4lq..+3})
        #pragma unroll
        for (int w = 0; w < 2; w++) {
          if (t0 + w*32 <= rr + 31) {
            bf16x8 av[4];
            #pragma unroll
            for (int jj = 0; jj < 4; jj++) {
              const char* vrow = VsB + w*4096 + (jj*16 + lm)*64;
              unsigned long long q0 = *reinterpret_cast<const unsigned long long*>(vrow + lq*8);
              unsigned long long q1 = *reinterpret_cast<const unsigned long long*>(vrow + 32 + lq*8);
              union { unsigned long long q[2]; bf16x8 v; } u;
              u.q[0] = q0; u.q[1] = q1;
              av[jj] = u.v;
            }
            #pragma unroll
            for (int i = 0; i < 2; i++) {
              if (jm[i] > w*2) {
                union { unsigned int u[4]; bf16x8 v; } pu;
                pu.u[0] = pb[i][w][0]; pu.u[1] = pb[i][w][1];
                pu.u[2] = pb[i][w][2]; pu.u[3] = pb[i][w][3];
                #pragma unroll
                for (int jj = 0; jj < 4; jj++)
                  O[s][i][jj] = __builtin_amdgcn_mfma_f32_16x16x32_bf16(
                      av[jj], pu.v, O[s][i][jj], 0, 0, 0);
              }
            }
          }
        }
      }
    }
    __syncthreads();   // compute(t) done; stage(t+1) drained
  }

  // epilogue: reduce l over lq groups (lanes 16/32 apart share m), scale, store
  #pragma unroll
  for (int s = 0; s < 2; s++) {
    const int rr = s ? rB : rA;
    #pragma unroll
    for (int i = 0; i < 2; i++) {
      float sum = l[s][i];
      sum += __shfl_xor(sum, 16, 64);
      sum += __shfl_xor(sum, 32, 64);
      const float inv = 1.0f / sum;
      const int srow = rr + i*16 + lm;
      #pragma unroll
      for (int jj = 0; jj < 4; jj++) {
        uint2 e;
        e.x = pkbf(O[s][i][jj][0] * inv, O[s][i][jj][1] * inv);
        e.y = pkbf(O[s][i][jj][2] * inv, O[s][i][jj][3] * inv);
        *reinterpret_cast<uint2*>(
            ctx + ((size_t)srow * BATCH + b) * EMB + h*HD + jj*16 + lq*4) = e;
      }
    }
  }
}

// ---------------- Output GEMM: ctx x outWt + bias -> f32, double-buffered ----------------

__global__ __launch_bounds__(256) void gemm_out(
    const unsigned short* __restrict__ A,
    const unsigned short* __restrict__ Wt,
    const float* __restrict__ bias,
    float* __restrict__ out) {
  __shared__ __align__(16) unsigned short As[2][128 * 64];
  __shared__ __align__(16) unsigned short Bs[2][128 * 64];
  const int tid = threadIdx.x;
  const int n0 = blockIdx.x * 128;
  const int m0 = blockIdx.y * 128;
  const int wave = tid >> 6, lane = tid & 63;
  const int wm = (wave >> 1) * 64, wn = (wave & 1) * 64;
  const int lm = lane & 15, lq = lane >> 4;
  const int K = 2048;

  const int srow = tid >> 3;
  const int gch  = (tid & 7) ^ (srow & 7);
  const unsigned short* Ab = A  + (size_t)(m0 + srow) * K + gch * 8;
  const unsigned short* Bb = Wt + (size_t)(n0 + srow) * K + gch * 8;

  f32x4 acc[4][4] = {};

  #pragma unroll
  for (int rep = 0; rep < 4; rep++) {
    async_copy16(Ab + (size_t)rep * 32 * K, As[0] + (size_t)(tid + 256 * rep) * 8);
    async_copy16(Bb + (size_t)rep * 32 * K, Bs[0] + (size_t)(tid + 256 * rep) * 8);
  }
  __syncthreads();

  for (int kt = 0; kt < 32; kt++) {
    const int buf = kt & 1;
    if (kt + 1 < 32) {
      const int k1 = (kt + 1) * 64;
      #pragma unroll
      for (int rep = 0; rep < 4; rep++) {
        async_copy16(Ab + (size_t)rep * 32 * K + k1, As[buf ^ 1] + (size_t)(tid + 256 * rep) * 8);
        async_copy16(Bb + (size_t)rep * 32 * K + k1, Bs[buf ^ 1] + (size_t)(tid + 256 * rep) * 8);
      }
    }
    #pragma unroll
    for (int ks = 0; ks < 2; ks++) {
      bf16x8 a[4], b[4];
      #pragma unroll
      for (int i = 0; i < 4; i++) {
        const int R = wm + i*16 + lm;
        a[i] = *reinterpret_cast<const bf16x8*>(
            As[buf] + (size_t)R * 64 + (((ks*4 + lq) ^ (R & 7)) * 8));
      }
      #pragma unroll
      for (int j = 0; j < 4; j++) {
        const int R = wn + j*16 + lm;
        b[j] = *reinterpret_cast<const bf16x8*>(
            Bs[buf] + (size_t)R * 64 + (((ks*4 + lq) ^ (R & 7)) * 8));
      }
      #pragma unroll
      for (int i = 0; i < 4; i++)
        #pragma unroll
        for (int j = 0; j < 4; j++)
          acc[i][j] = __builtin_amdgcn_mfma_f32_16x16x32_bf16(a[i], b[j], acc[i][j], 0, 0, 0);
    }
    __syncthreads();
  }

  #pragma unroll
  for (int j = 0; j < 4; j++) {
    const int n = n0 + wn + j*16 + lm;
    const float bv = bias[n];
    #pragma unroll
    for (int i = 0; i < 4; i++) {
      #pragma unroll
      for (int r = 0; r < 4; r++) {
        const int m = m0 + wm + i*16 + lq*4 + r;
        out[(size_t)m * EMB + n] = acc[i][j][r] + bv;
      }
    }
  }
}

// ---------------- host launcher ----------------

extern "C" void kernel_launch(void* const* d_in, const int* in_sizes, int n_in,
                              void* d_out, int out_size, void* d_ws, size_t ws_size,
                              hipStream_t stream) {
  const float* hidden = (const float*)d_in[0];
  const float* qkv_w  = (const float*)d_in[1];
  const float* qkv_b  = (const float*)d_in[2];
  const float* out_w  = (const float*)d_in[3];
  const float* out_b  = (const float*)d_in[4];
  float* out = (float*)d_out;

  unsigned short* ws = (unsigned short*)d_ws;
  unsigned short* hbf   = ws;                                  // 4096*2048
  unsigned short* qkvwT = hbf   + (size_t)M_ROWS * EMB;        // 6144*2048
  unsigned short* outwT = qkvwT + (size_t)QKV_N * EMB;         // 2048*2048
  unsigned short* Qb    = outwT + (size_t)EMB * EMB;           // 64*2048*64 each
  unsigned short* Kb    = Qb    + (size_t)64 * S_LEN * HD;
  unsigned short* Vb    = Kb    + (size_t)64 * S_LEN * HD;
  unsigned short* VTb   = Vb    + (size_t)64 * S_LEN * HD;
  unsigned short* ctx   = VTb   + (size_t)64 * S_LEN * HD;     // 4096*2048

  // 1. casts / transposes
  cast_to_bf16<<<(M_ROWS * EMB / 4) / 256, 256, 0, stream>>>(hidden, hbf, M_ROWS * EMB / 4);
  transpose_cast2<<<dim3(QKV_N / 32, EMB / 32, 2), 256, 0, stream>>>(qkv_w, out_w, qkvwT, outwT);

  // 2. fused QKV projection + bias + RoPE (+softmax scale on Q) + scatter
  gemm_qkv<<<dim3(QKV_N / 128, M_ROWS / 128), 256, 0, stream>>>(hbf, qkvwT, qkv_b, Qb, Kb, Vb);

  // 3. V transpose
  transpose_v<<<dim3(S_LEN / 64, 64), 256, 0, stream>>>(Vb, VTb);

  // 4. causal flash attention (register-direct P, dbuf K/V, 1 barrier/tile)
  attn_kernel<<<dim3(64, 8), 256, 0, stream>>>(Qb, Kb, VTb, ctx);

  // 5. output projection (double-buffered)
  gemm_out<<<dim3(EMB / 128, M_ROWS / 128), 256, 0, stream>>>(ctx, outwT, out_b, out);
}

// Round 9
// 380.557 us; speedup vs baseline: 1.1036x; 1.0883x over previous
//
#include <hip/hip_runtime.h>
#include <hip/hip_bf16.h>

// Problem constants (S=2048, B=2, E=2048, H=32, D=64)
#define S_LEN 2048
#define BATCH 2
#define EMB   2048
#define NH    32
#define HD    64
#define M_ROWS (S_LEN * BATCH)   // 4096
#define QKV_N  (3 * EMB)         // 6144

typedef short bf16x8 __attribute__((ext_vector_type(8)));
typedef float f32x4  __attribute__((ext_vector_type(4)));

__device__ __forceinline__ unsigned short f2bf(float f) {
  unsigned int u = __float_as_uint(f);
  u += 0x7fffu + ((u >> 16) & 1u);       // round-to-nearest-even
  return (unsigned short)(u >> 16);
}
__device__ __forceinline__ unsigned int pkbf(float a, float b) {
  __hip_bfloat162 t = __float22bfloat162_rn(float2{a, b});   // v_cvt_pk_bf16_f32
  return *reinterpret_cast<unsigned int*>(&t);
}
__device__ __forceinline__ void async_copy16(const void* g, void* lds) {
  __builtin_amdgcn_global_load_lds(
      (const __attribute__((address_space(1))) void*)g,
      (__attribute__((address_space(3))) void*)lds, 16, 0, 0);
}

#if __has_builtin(__builtin_amdgcn_exp2f)
#define EXP2F(x) __builtin_amdgcn_exp2f(x)
#else
#define EXP2F(x) __expf((x) * 0.6931471805599453f)
#endif

// ---------------- prep kernels ----------------

__global__ __launch_bounds__(256) void cast_to_bf16(
    const float* __restrict__ in, unsigned short* __restrict__ out, int n4) {
  int i = blockIdx.x * 256 + threadIdx.x;
  if (i >= n4) return;
  float4 v = reinterpret_cast<const float4*>(in)[i];
  ushort4 o;
  o.x = f2bf(v.x); o.y = f2bf(v.y); o.z = f2bf(v.z); o.w = f2bf(v.w);
  reinterpret_cast<ushort4*>(out)[i] = o;
}

// both weight transposes, tight grid: x<192 -> qkv_w [E][6144], else out_w [E][2048]
__global__ __launch_bounds__(256) void transpose_cast2(
    const float* __restrict__ qkv_w, const float* __restrict__ out_w,
    unsigned short* __restrict__ qkvwT, unsigned short* __restrict__ outwT) {
  __shared__ float tile[32][33];
  const int bx = blockIdx.x;
  const float* in;
  unsigned short* out;
  int C, bc;
  if (bx < 192) { in = qkv_w; out = qkvwT; C = QKV_N; bc = bx * 32; }
  else          { in = out_w; out = outwT; C = EMB;   bc = (bx - 192) * 32; }
  const int br = blockIdx.y * 32;
  const int tx = threadIdx.x & 31, ty = threadIdx.x >> 5;   // ty 0..7
  #pragma unroll
  for (int rr = ty; rr < 32; rr += 8)
    tile[rr][tx] = in[(size_t)(br + rr) * C + bc + tx];
  __syncthreads();
  #pragma unroll
  for (int rr = ty; rr < 32; rr += 8)
    out[(size_t)(bc + rr) * EMB + br + tx] = f2bf(tile[tx][rr]);
}

// ---------------- QKV GEMM, BK=64, XOR-swizzled LDS, fused bias+RoPE+scatter ----
// Q additionally pre-scaled by (1/8)*log2(e) so attention's exp2 needs no mul.

__global__ __launch_bounds__(256) void gemm_qkv(
    const unsigned short* __restrict__ A,
    const unsigned short* __restrict__ Wt,
    const float* __restrict__ bias,
    unsigned short* __restrict__ Qo,
    unsigned short* __restrict__ Ko,
    unsigned short* __restrict__ Vo) {
  __shared__ __align__(16) unsigned short As[128 * 64];
  __shared__ __align__(16) unsigned short Bs[128 * 64];
  const int tid = threadIdx.x;
  const int n0 = blockIdx.x * 128;
  const int m0 = blockIdx.y * 128;
  const int wave = tid >> 6, lane = tid & 63;
  const int wm = (wave >> 1) * 64, wn = (wave & 1) * 64;
  const int lm = lane & 15, lq = lane >> 4;
  const int K = 2048;

  const int srow = tid >> 3;                       // 0..31
  const int gch  = (tid & 7) ^ (srow & 7);
  const unsigned short* Ab = A  + (size_t)(m0 + srow) * K + gch * 8;
  const unsigned short* Bb = Wt + (size_t)(n0 + srow) * K + gch * 8;

  f32x4 acc[4][4] = {};

  for (int k0 = 0; k0 < K; k0 += 64) {
    #pragma unroll
    for (int rep = 0; rep < 4; rep++) {
      async_copy16(Ab + (size_t)rep * 32 * K + k0, As + (size_t)(tid + 256 * rep) * 8);
      async_copy16(Bb + (size_t)rep * 32 * K + k0, Bs + (size_t)(tid + 256 * rep) * 8);
    }
    __syncthreads();
    #pragma unroll
    for (int ks = 0; ks < 2; ks++) {
      bf16x8 a[4], b[4];
      #pragma unroll
      for (int i = 0; i < 4; i++) {
        const int R = wm + i*16 + lm;
        a[i] = *reinterpret_cast<const bf16x8*>(
            As + (size_t)R * 64 + (((ks*4 + lq) ^ (R & 7)) * 8));
      }
      #pragma unroll
      for (int j = 0; j < 4; j++) {
        const int R = wn + j*16 + lm;
        b[j] = *reinterpret_cast<const bf16x8*>(
            Bs + (size_t)R * 64 + (((ks*4 + lq) ^ (R & 7)) * 8));
      }
      #pragma unroll
      for (int i = 0; i < 4; i++)
        #pragma unroll
        for (int j = 0; j < 4; j++)
          acc[i][j] = __builtin_amdgcn_mfma_f32_16x16x32_bf16(a[i], b[j], acc[i][j], 0, 0, 0);
    }
    __syncthreads();
  }

  const int which = n0 >> 11;   // 0=q 1=k 2=v, uniform per block
  unsigned short* dst = (which == 0) ? Qo : (which == 1) ? Ko : Vo;
  float bv[4];
  #pragma unroll
  for (int j = 0; j < 4; j++) bv[j] = bias[n0 + wn + j*16 + lm];

  if (which < 2) {
    const float osc = (which == 0) ? 0.18033688011112042f : 1.0f;  // (1/8)*log2(e)
    #pragma unroll
    for (int j = 0; j < 2; j++) {
      const int n = n0 + wn + j*16 + lm;
      const int e = n & (EMB - 1), h = e >> 6, d = e & 63;   // d < 32
      const float invf = EXP2F((float)d * -0.4152410118609203f);  // 10000^(-d/32)
      #pragma unroll
      for (int i = 0; i < 4; i++) {
        #pragma unroll
        for (int r = 0; r < 4; r++) {
          const int m = m0 + wm + i*16 + lq*4 + r;
          const int s = m >> 1, b = m & 1;
          const float v1 = acc[i][j][r]   + bv[j];
          const float v2 = acc[i][j+2][r] + bv[j+2];
          float sn, cs;
          __sincosf((float)s * invf, &sn, &cs);
          const size_t base = (((size_t)b * NH + h) * S_LEN + s) * HD + d;
          dst[base]      = f2bf((v1 * cs - v2 * sn) * osc);
          dst[base + 32] = f2bf((v2 * cs + v1 * sn) * osc);
        }
      }
    }
  } else {
    #pragma unroll
    for (int j = 0; j < 4; j++) {
      const int n = n0 + wn + j*16 + lm;
      const int e = n & (EMB - 1), h = e >> 6, d = e & 63;
      #pragma unroll
      for (int i = 0; i < 4; i++) {
        #pragma unroll
        for (int r = 0; r < 4; r++) {
          const int m = m0 + wm + i*16 + lq*4 + r;
          const int s = m >> 1, b = m & 1;
          dst[(((size_t)b * NH + h) * S_LEN + s) * HD + d] = f2bf(acc[i][j][r] + bv[j]);
        }
      }
    }
  }
}

// ---------------- V [B,H,S,D] -> VT [B,H,D,S] ----------------

__global__ __launch_bounds__(256) void transpose_v(
    const unsigned short* __restrict__ V, unsigned short* __restrict__ VT) {
  __shared__ unsigned short t[64][65];
  const int bh = blockIdx.y;
  const int s0 = blockIdx.x * 64;
  const int tx = threadIdx.x & 63, ty = threadIdx.x >> 6;  // ty 0..3
  const unsigned short* src = V + ((size_t)bh * S_LEN + s0) * HD;
  #pragma unroll
  for (int r = ty; r < 64; r += 4)
    t[r][tx] = src[(size_t)r * HD + tx];
  __syncthreads();
  unsigned short* dst = VT + (size_t)bh * HD * S_LEN + s0;
  #pragma unroll
  for (int r = ty; r < 64; r += 4)
    dst[(size_t)r * S_LEN + tx] = t[tx][r];
}

// ---------------- Flash attention (causal), register-direct P, unpaired strips ----
// Block = (head, one 128-row strip), 4 waves x 32 rows; grid (64,16) = 1024
// blocks, heavy strips launched FIRST (strip = 15 - blockIdx.y) so the causal
// imbalance back-fills. S^T = mfma(K,Q) -> exp2 -> pack in regs -> O^T = V^T P^T.
// V LDS staging XOR-swizzled (16B chunk ^ ((row>>1)&3)) so the b64 A-frag
// reads spread 4 bank-pairs x 2 lanes (free). K/V dbuf, one barrier per tile.

__global__ __launch_bounds__(256) void attn_kernel(
    const unsigned short* __restrict__ Q,
    const unsigned short* __restrict__ K,
    const unsigned short* __restrict__ VT,
    unsigned short* __restrict__ ctx) {
  const int bh = blockIdx.x;               // b*32+h
  const int strip = 15 - blockIdx.y;       // heavy first
  const int tid = threadIdx.x;
  const int wave = tid >> 6, lane = tid & 63;
  const int lm = lane & 15, lq = lane >> 4;
  const int b = bh >> 5, h = bh & 31;
  const char* Qb8 = (const char*)(Q  + (size_t)bh * S_LEN * HD);
  const char* Kb8 = (const char*)(K  + (size_t)bh * S_LEN * HD);
  const char* Vb8 = (const char*)(VT + (size_t)bh * HD * S_LEN);

  __shared__ __align__(16) unsigned short Ks[2][2][64][32];  // [buf][half][row][32]
  __shared__ __align__(16) unsigned short Vs[2][2][64][32];

  const int rr = strip * 128 + wave * 32;
  const int nt = strip * 2 + 2;

  // staging: row = tid>>2, 16B chunk = tid&3; V source chunk XOR-swizzled
  const int srw = tid >> 2;
  const int kc16 = (tid & 3) * 16;
  const int vc16 = ((tid & 3) ^ ((srw >> 1) & 3)) * 16;

  // Q fragments (rows rr+i*16+lm, k-contiguous) — used as MFMA B operand
  bf16x8 qf[2][2];                         // [i][ks]
  #pragma unroll
  for (int i = 0; i < 2; i++)
    #pragma unroll
    for (int ks = 0; ks < 2; ks++)
      qf[i][ks] = *reinterpret_cast<const bf16x8*>(
          Qb8 + (size_t)(rr + i*16 + lm) * 128 + ks*64 + lq*16);

  f32x4 O[2][4] = {};                      // [i][d-tile] — O^T C-layout
  float l[2] = {};

  // stage tile 0 into buf 0
  {
    char* kd = (char*)&Ks[0][0][0][0];
    char* vd = (char*)&Vs[0][0][0][0];
    async_copy16(Kb8 + (size_t)srw * 128       + kc16, kd        + tid*16);
    async_copy16(Kb8 + (size_t)srw * 128 + 64  + kc16, kd + 4096 + tid*16);
    async_copy16(Vb8 + (size_t)srw * 4096      + vc16, vd        + tid*16);
    async_copy16(Vb8 + (size_t)srw * 4096 + 64 + vc16, vd + 4096 + tid*16);
  }
  __syncthreads();

  for (int t = 0; t < nt; t++) {
    const int t0 = t * 64;
    const int buf = t & 1;

    if (t + 1 < nt) {
      const int t1 = t0 + 64;
      char* kd = (char*)&Ks[buf ^ 1][0][0][0];
      char* vd = (char*)&Vs[buf ^ 1][0][0][0];
      async_copy16(Kb8 + (size_t)(t1 + srw) * 128       + kc16, kd        + tid*16);
      async_copy16(Kb8 + (size_t)(t1 + srw) * 128 + 64  + kc16, kd + 4096 + tid*16);
      async_copy16(Vb8 + (size_t)srw * 4096 + t1*2      + vc16, vd        + tid*16);
      async_copy16(Vb8 + (size_t)srw * 4096 + t1*2 + 64 + vc16, vd + 4096 + tid*16);
    }

    const char* KsB = (const char*)&Ks[buf][0][0][0];
    const char* VsB = (const char*)&Vs[buf][0][0][0];

    const bool clean = (t0 + 63 <= rr);
    int jm[2];
    jm[1] = clean ? 4 : (((rr + 31 - t0) >> 4) + 1);
    jm[0] = clean ? 4 : ((t0 > rr + 15) ? 0 : (((rr + 15 - t0) >> 4) + 1));

    // S^T = K · Q^T  (kf in A position, qf in B position)
    f32x4 sc[2][4] = {};
    #pragma unroll
    for (int ks = 0; ks < 2; ks++) {
      bf16x8 kf[4];
      #pragma unroll
      for (int j = 0; j < 4; j++)
        if (j < jm[1])
          kf[j] = *reinterpret_cast<const bf16x8*>(
              KsB + ks*4096 + (j*16 + lm)*64 + lq*16);
      #pragma unroll
      for (int i = 0; i < 2; i++)
        #pragma unroll
        for (int j = 0; j < 4; j++)
          if (j < jm[i])
            sc[i][j] = __builtin_amdgcn_mfma_f32_16x16x32_bf16(
                kf[j], qf[i][ks], sc[i][j], 0, 0, 0);
    }

    // exp2 + pack P^T directly into PV B-fragments (no LDS)
    unsigned int pb[2][2][4];              // [i][t-window][reg]
    #pragma unroll
    for (int i = 0; i < 2; i++) {
      #pragma unroll
      for (int j = 0; j < 4; j++) {
        const int w = j >> 1, rbase = (j & 1) * 2;
        if (j < jm[i]) {
          const bool full = clean || (t0 + j*16 + 15 <= rr + i*16);
          float pe[4];
          #pragma unroll
          for (int r = 0; r < 4; r++) {
            float v = EXP2F(sc[i][j][r]);
            if (!full) {
              const int tt = t0 + j*16 + lq*4 + r;
              const int mm = rr + i*16 + lm;
              v = (tt <= mm) ? v : 0.0f;
            }
            pe[r] = v;
          }
          l[i] += (pe[0] + pe[1]) + (pe[2] + pe[3]);
          pb[i][w][rbase]     = pkbf(pe[0], pe[1]);
          pb[i][w][rbase + 1] = pkbf(pe[2], pe[3]);
        } else {
          pb[i][w][rbase] = 0; pb[i][w][rbase + 1] = 0;
        }
      }
    }

    // O^T += V^T · P^T  (A-frag reads swizzled t-slices; shared across i)
    #pragma unroll
    for (int w = 0; w < 2; w++) {
      if (t0 + w*32 <= rr + 31) {
        bf16x8 av[4];
        #pragma unroll
        for (int jj = 0; jj < 4; jj++) {
          const int row = jj*16 + lm;
          const char* vrow = VsB + w*4096 + row*64;
          const int f = ((row >> 1) & 3) << 1;          // even XOR key
          unsigned long long q0 = *reinterpret_cast<const unsigned long long*>(
              vrow + (lq ^ f) * 8);
          unsigned long long q1 = *reinterpret_cast<const unsigned long long*>(
              vrow + ((4 + lq) ^ f) * 8);
          union { unsigned long long q[2]; bf16x8 v; } u;
          u.q[0] = q0; u.q[1] = q1;
          av[jj] = u.v;
        }
        #pragma unroll
        for (int i = 0; i < 2; i++) {
          if (jm[i] > w*2) {
            union { unsigned int u[4]; bf16x8 v; } pu;
            pu.u[0] = pb[i][w][0]; pu.u[1] = pb[i][w][1];
            pu.u[2] = pb[i][w][2]; pu.u[3] = pb[i][w][3];
            #pragma unroll
            for (int jj = 0; jj < 4; jj++)
              O[i][jj] = __builtin_amdgcn_mfma_f32_16x16x32_bf16(
                  av[jj], pu.v, O[i][jj], 0, 0, 0);
          }
        }
      }
    }
    __syncthreads();   // compute(t) done; stage(t+1) drained
  }

  // epilogue: reduce l over lq groups (lanes 16/32 apart share m), scale, store
  #pragma unroll
  for (int i = 0; i < 2; i++) {
    float sum = l[i];
    sum += __shfl_xor(sum, 16, 64);
    sum += __shfl_xor(sum, 32, 64);
    const float inv = 1.0f / sum;
    const int srow = rr + i*16 + lm;
    #pragma unroll
    for (int jj = 0; jj < 4; jj++) {
      uint2 e;
      e.x = pkbf(O[i][jj][0] * inv, O[i][jj][1] * inv);
      e.y = pkbf(O[i][jj][2] * inv, O[i][jj][3] * inv);
      *reinterpret_cast<uint2*>(
          ctx + ((size_t)srow * BATCH + b) * EMB + h*HD + jj*16 + lq*4) = e;
    }
  }
}

// ---------------- Output GEMM (R6 single-buffer BK=64 XOR-swizzled) ----------------

__global__ __launch_bounds__(256) void gemm_out(
    const unsigned short* __restrict__ A,
    const unsigned short* __restrict__ Wt,
    const float* __restrict__ bias,
    float* __restrict__ out) {
  __shared__ __align__(16) unsigned short As[128 * 64];
  __shared__ __align__(16) unsigned short Bs[128 * 64];
  const int tid = threadIdx.x;
  const int n0 = blockIdx.x * 128;
  const int m0 = blockIdx.y * 128;
  const int wave = tid >> 6, lane = tid & 63;
  const int wm = (wave >> 1) * 64, wn = (wave & 1) * 64;
  const int lm = lane & 15, lq = lane >> 4;
  const int K = 2048;

  const int srow = tid >> 3;
  const int gch  = (tid & 7) ^ (srow & 7);
  const unsigned short* Ab = A  + (size_t)(m0 + srow) * K + gch * 8;
  const unsigned short* Bb = Wt + (size_t)(n0 + srow) * K + gch * 8;

  f32x4 acc[4][4] = {};

  for (int k0 = 0; k0 < K; k0 += 64) {
    #pragma unroll
    for (int rep = 0; rep < 4; rep++) {
      async_copy16(Ab + (size_t)rep * 32 * K + k0, As + (size_t)(tid + 256 * rep) * 8);
      async_copy16(Bb + (size_t)rep * 32 * K + k0, Bs + (size_t)(tid + 256 * rep) * 8);
    }
    __syncthreads();
    #pragma unroll
    for (int ks = 0; ks < 2; ks++) {
      bf16x8 a[4], b[4];
      #pragma unroll
      for (int i = 0; i < 4; i++) {
        const int R = wm + i*16 + lm;
        a[i] = *reinterpret_cast<const bf16x8*>(
            As + (size_t)R * 64 + (((ks*4 + lq) ^ (R & 7)) * 8));
      }
      #pragma unroll
      for (int j = 0; j < 4; j++) {
        const int R = wn + j*16 + lm;
        b[j] = *reinterpret_cast<const bf16x8*>(
            Bs + (size_t)R * 64 + (((ks*4 + lq) ^ (R & 7)) * 8));
      }
      #pragma unroll
      for (int i = 0; i < 4; i++)
        #pragma unroll
        for (int j = 0; j < 4; j++)
          acc[i][j] = __builtin_amdgcn_mfma_f32_16x16x32_bf16(a[i], b[j], acc[i][j], 0, 0, 0);
    }
    __syncthreads();
  }

  #pragma unroll
  for (int j = 0; j < 4; j++) {
    const int n = n0 + wn + j*16 + lm;
    const float bv = bias[n];
    #pragma unroll
    for (int i = 0; i < 4; i++) {
      #pragma unroll
      for (int r = 0; r < 4; r++) {
        const int m = m0 + wm + i*16 + lq*4 + r;
        out[(size_t)m * EMB + n] = acc[i][j][r] + bv;
      }
    }
  }
}

// ---------------- host launcher ----------------

extern "C" void kernel_launch(void* const* d_in, const int* in_sizes, int n_in,
                              void* d_out, int out_size, void* d_ws, size_t ws_size,
                              hipStream_t stream) {
  const float* hidden = (const float*)d_in[0];
  const float* qkv_w  = (const float*)d_in[1];
  const float* qkv_b  = (const float*)d_in[2];
  const float* out_w  = (const float*)d_in[3];
  const float* out_b  = (const float*)d_in[4];
  float* out = (float*)d_out;

  unsigned short* ws = (unsigned short*)d_ws;
  unsigned short* hbf   = ws;                                  // 4096*2048
  unsigned short* qkvwT = hbf   + (size_t)M_ROWS * EMB;        // 6144*2048
  unsigned short* outwT = qkvwT + (size_t)QKV_N * EMB;         // 2048*2048
  unsigned short* Qb    = outwT + (size_t)EMB * EMB;           // 64*2048*64 each
  unsigned short* Kb    = Qb    + (size_t)64 * S_LEN * HD;
  unsigned short* Vb    = Kb    + (size_t)64 * S_LEN * HD;
  unsigned short* VTb   = Vb    + (size_t)64 * S_LEN * HD;
  unsigned short* ctx   = VTb   + (size_t)64 * S_LEN * HD;     // 4096*2048

  // 1. casts / transposes
  cast_to_bf16<<<(M_ROWS * EMB / 4) / 256, 256, 0, stream>>>(hidden, hbf, M_ROWS * EMB / 4);
  transpose_cast2<<<dim3(256, EMB / 32), 256, 0, stream>>>(qkv_w, out_w, qkvwT, outwT);

  // 2. fused QKV projection + bias + RoPE (+softmax scale on Q) + scatter
  gemm_qkv<<<dim3(QKV_N / 128, M_ROWS / 128), 256, 0, stream>>>(hbf, qkvwT, qkv_b, Qb, Kb, Vb);

  // 3. V transpose
  transpose_v<<<dim3(S_LEN / 64, 64), 256, 0, stream>>>(Vb, VTb);

  // 4. causal flash attention (unpaired strips, heavy-first, dbuf K/V)
  attn_kernel<<<dim3(64, 16), 256, 0, stream>>>(Qb, Kb, VTb, ctx);

  // 5. output projection
  gemm_out<<<dim3(EMB / 128, M_ROWS / 128), 256, 0, stream>>>(ctx, outwT, out_b, out);
}